// Round 15
// baseline (434.190 us; speedup 1.0000x reference)
//
#include <hip/hip_runtime.h>

// GraphSAGE: 3x SAGEConv(mean) + linear head.
// N=100000 nodes, E=3200000 edges, dims 64 -> 64 -> 32 -> 16 -> 1.
// Round 15 = round 14 resubmitted (container infra failure; no result).
//  - aggt_k: agg(layer l) FUSED with transform(layer l+1). h stays in LDS,
//    never hits global (h1/h2 buffers deleted; t1/t2 kernels deleted).
//  - r stored bf16 (like g): halves r traffic everywhere. (agg was L3-BW
//    bound: 168MB fetch @ 2.6TB/s; fewer bytes is the only lever.)
//  - part1_k stages the dst chunk in LDS across its two passes (-12.8MB).
// Proven structure kept: counting-sort CSR build (block-exclusive full-line
// writes via LDS staging), PULL gather agg, transform-first (agg-linearity).

#define NN 100000
#define BSH 8                       // bucket = dst >> 8 (256 nodes)
#define NBK ((NN + 255) >> 8)       // 391 buckets
#define HB 256                      // partition chunks / slices per bucket
#define SRCMASK 0x1FFFF             // 17 bits, N=100000 < 2^17
#define DLSH 17                     // dl = dst & 255 packed at bit 17
#define SPCAP 12500                 // = E/HB exactly (chunk size)
#define LADJ_CAP 10240              // bucket adjacency LDS capacity (mean 8184)

__device__ __forceinline__ unsigned f2bf(float f) {   // RNE fp32->bf16
    unsigned u = __float_as_uint(f);
    u += 0x7fffu + ((u >> 16) & 1u);
    return u >> 16;
}
__device__ __forceinline__ float bflo(unsigned u) { return __uint_as_float(u << 16); }
__device__ __forceinline__ float bfhi(unsigned u) { return __uint_as_float(u & 0xffff0000u); }
__device__ __forceinline__ float bfs(unsigned short s) { return __uint_as_float((unsigned)s << 16); }

// ---- fused: per-chunk bucket histogram + local scan + LDS-staged place ----
// Block c owns edges [b0,e0) and pair slots [b0,e0). dst chunk cached in LDS
// across both passes. All global writes contiguous block-exclusive lines.
__global__ void part1_k(const int* __restrict__ src, const int* __restrict__ dst,
                        int E, int* __restrict__ gcnt, int* __restrict__ goff,
                        unsigned* __restrict__ pair) {
    __shared__ unsigned spair[SPCAP];
    __shared__ int sdst[SPCAP];
    __shared__ int lh[NBK];
    __shared__ int part[512];
    int c = blockIdx.x, tid = threadIdx.x;
    int chunk = (E + HB - 1) / HB;
    int b0 = c * chunk, e0 = min(b0 + chunk, E);
    int n = e0 - b0;
    if (tid < NBK) lh[tid] = 0;
    __syncthreads();
    for (int i = tid; i < n; i += 512) {
        int dv = dst[b0 + i];
        sdst[i] = dv;
        atomicAdd(&lh[dv >> BSH], 1);
    }
    __syncthreads();
    int cnt = (tid < NBK) ? lh[tid] : 0;
    part[tid] = cnt;
    __syncthreads();
    for (int d = 1; d < 512; d <<= 1) {
        int t = (tid >= d) ? part[tid - d] : 0;
        __syncthreads();
        part[tid] += t;
        __syncthreads();
    }
    int run = (tid == 0) ? 0 : part[tid - 1];
    if (tid < NBK) {
        gcnt[(size_t)c * NBK + tid] = cnt;   // counts, c-major (contiguous)
        goff[(size_t)c * NBK + tid] = run;   // local offsets, c-major
        lh[tid] = run;                       // becomes cursor
    }
    __syncthreads();
    for (int i = tid; i < n; i += 512) {
        int dv = sdst[i];
        int sv = src[b0 + i];
        int p = atomicAdd(&lh[dv >> BSH], 1);          // bucket-grouped local pos
        spair[p] = (unsigned)sv | ((unsigned)(dv & 255) << DLSH);
    }
    __syncthreads();
    for (int i = tid; i < n; i += 512) pair[b0 + i] = spair[i];   // full-line writes
}

// ---- per-bucket totals + exclusive scan -> adj base per bucket ----
__global__ void bsum_k(const int* __restrict__ gcnt, int* __restrict__ bb, int E) {
    __shared__ int part[512];
    int tid = threadIdx.x;
    int s = 0;
    if (tid < NBK)
        for (int c = 0; c < HB; ++c) s += gcnt[(size_t)c * NBK + tid];
    part[tid] = s;
    __syncthreads();
    for (int d = 1; d < 512; d <<= 1) {
        int t = (tid >= d) ? part[tid - d] : 0;
        __syncthreads();
        part[tid] += t;
        __syncthreads();
    }
    if (tid < NBK) bb[tid] = part[tid] - s;   // exclusive prefix
    if (tid == 0) bb[NBK] = E;
}

// ---- per-bucket counting sort -> per-node CSR (adj, off, inv) ----
__global__ void sort2_k(const unsigned* __restrict__ pair, const int* __restrict__ goff,
                        const int* __restrict__ bb, int* __restrict__ adj,
                        int* __restrict__ off, float* __restrict__ inv, int N, int E) {
    __shared__ int ladj[LADJ_CAP];
    __shared__ int sls[HB], sle[HB];
    __shared__ int lcur[256];
    __shared__ int part[256];
    int b = blockIdx.x, tid = threadIdx.x;   // blockDim == HB == 256
    int chunk = (E + HB - 1) / HB;
    int b0c = tid * chunk, e0c = min(b0c + chunk, E);
    int ls = b0c + goff[(size_t)tid * NBK + b];
    int le = (b + 1 < NBK) ? (b0c + goff[(size_t)tid * NBK + b + 1]) : e0c;
    sls[tid] = ls; sle[tid] = le;
    lcur[tid] = 0;
    __syncthreads();
    for (int i = ls; i < le; ++i)
        atomicAdd(&lcur[pair[i] >> DLSH], 1);          // count per node
    __syncthreads();
    int cn = lcur[tid];
    part[tid] = cn;
    __syncthreads();
    for (int d = 1; d < 256; d <<= 1) {
        int t = (tid >= d) ? part[tid - d] : 0;
        __syncthreads();
        part[tid] += t;
        __syncthreads();
    }
    int run = part[tid] - cn;                          // exclusive prefix
    int base = bb[b];
    int total = bb[b + 1] - base;
    int v = (b << BSH) + tid;
    if (v < N) { off[v] = base + run; inv[v] = 1.f / (float)max(cn, 1); }
    if (b == NBK - 1 && tid == 0) off[N] = E;
    lcur[tid] = run;                                   // becomes cursor
    __syncthreads();
    for (int i = sls[tid]; i < sle[tid]; ++i) {
        unsigned u = pair[i];
        int p = atomicAdd(&lcur[u >> DLSH], 1);
        int val = u & SRCMASK;
        if (p < LADJ_CAP) ladj[p] = val;               // staged (always, in practice)
        else adj[base + p] = val;                      // safety fallback
    }
    __syncthreads();
    int lim = min(total, LADJ_CAP);
    for (int i = tid; i < lim; i += 256) adj[base + i] = ladj[i];   // full-line writes
}

// ---- transform2: g = h@Wl (bf16 packed), r = h@Wr + b (bf16 packed) ----
template <int DIN, int DOUT>
__global__ void transform2_k(const float* __restrict__ h,
                             const float* __restrict__ Wl, const float* __restrict__ Wr,
                             const float* __restrict__ bias,
                             unsigned* __restrict__ g, unsigned* __restrict__ r, int N) {
    constexpr int JP = DOUT / 2;
    __shared__ float2 sWl[DIN * JP];
    __shared__ float2 sWr[DIN * JP];
    __shared__ float2 sb[JP];
    const float2* Wl2 = (const float2*)Wl;
    const float2* Wr2 = (const float2*)Wr;
    for (int i = threadIdx.x; i < DIN * JP; i += blockDim.x) { sWl[i] = Wl2[i]; sWr[i] = Wr2[i]; }
    if (threadIdx.x < JP) sb[threadIdx.x] = ((const float2*)bias)[threadIdx.x];
    __syncthreads();
    int idx = blockIdx.x * blockDim.x + threadIdx.x;
    int NP = N / 2;                    // N even
    if (idx >= NP * JP) return;
    int p = idx / JP, jp = idx % JP;
    int v0 = 2 * p, v1 = v0 + 1;
    const float* h0 = h + (size_t)v0 * DIN;
    const float* h1 = h + (size_t)v1 * DIN;
    float gl0x = 0, gl0y = 0, gl1x = 0, gl1y = 0;
    float gr0x = 0, gr0y = 0, gr1x = 0, gr1y = 0;
#pragma unroll
    for (int k = 0; k < DIN; ++k) {
        float2 wl = sWl[k * JP + jp];
        float2 wr = sWr[k * JP + jp];
        float a0 = h0[k], a1 = h1[k];
        gl0x = fmaf(a0, wl.x, gl0x); gl0y = fmaf(a0, wl.y, gl0y);
        gl1x = fmaf(a1, wl.x, gl1x); gl1y = fmaf(a1, wl.y, gl1y);
        gr0x = fmaf(a0, wr.x, gr0x); gr0y = fmaf(a0, wr.y, gr0y);
        gr1x = fmaf(a1, wr.x, gr1x); gr1y = fmaf(a1, wr.y, gr1y);
    }
    float2 bb = sb[jp];
    g[(size_t)v0 * JP + jp] = f2bf(gl0x) | (f2bf(gl0y) << 16);
    g[(size_t)v1 * JP + jp] = f2bf(gl1x) | (f2bf(gl1y) << 16);
    r[(size_t)v0 * JP + jp] = f2bf(gr0x + bb.x) | (f2bf(gr0y + bb.y) << 16);
    r[(size_t)v1 * JP + jp] = f2bf(gr1x + bb.x) | (f2bf(gr1y + bb.y) << 16);
}

// ---- fused agg(layer l) + transform(layer l+1) ----
// One wave per dst node (PULL gather of g, bf16). h = relu(mean + r) kept in
// LDS; then block computes gnext = h@Wln (bf16), rnext = h@Wrn + bn (bf16).
// One thread per (node, j, matrix): TOT = WAVES*DNEXT*2 <= 256.
template <int DOUT, int DNEXT, int WAVES>
__global__ void aggt_k(const unsigned* __restrict__ g, const int* __restrict__ off,
                       const int* __restrict__ adj, const float* __restrict__ invc,
                       const unsigned short* __restrict__ r,
                       const float* __restrict__ Wln, const float* __restrict__ Wrn,
                       const float* __restrict__ bn,
                       unsigned short* __restrict__ gnext, unsigned short* __restrict__ rnext,
                       int N) {
    constexpr int Q8 = DOUT / 8;
    constexpr int EPT = 64 / Q8;
    __shared__ float sagg[WAVES][DOUT];
    __shared__ float sh[WAVES][DOUT];
    __shared__ float sWl[DOUT * DNEXT];
    __shared__ float sWr[DOUT * DNEXT];
    __shared__ float sbn[DNEXT];
    for (int i = threadIdx.x; i < DOUT * DNEXT; i += blockDim.x) { sWl[i] = Wln[i]; sWr[i] = Wrn[i]; }
    if (threadIdx.x < DNEXT) sbn[threadIdx.x] = bn[threadIdx.x];
    int wid = threadIdx.x >> 6, lane = threadIdx.x & 63;
    int v = blockIdx.x * WAVES + wid;
    bool active = v < N;
    int q = lane & (Q8 - 1);
    int eg = lane / Q8;
    float acc[8] = {0, 0, 0, 0, 0, 0, 0, 0};
#define ACCU(U) do { \
        acc[0] += bflo(U.x); acc[1] += bfhi(U.x); \
        acc[2] += bflo(U.y); acc[3] += bfhi(U.y); \
        acc[4] += bflo(U.z); acc[5] += bfhi(U.z); \
        acc[6] += bflo(U.w); acc[7] += bfhi(U.w); } while (0)
    if (active) {
        int beg = off[v], end = off[v + 1];
        const uint4* g4 = (const uint4*)g;   // row = Q8 uint4s
        int i = beg + eg;
        for (; i + 3 * EPT < end; i += 4 * EPT) {
            int s0 = adj[i], s1 = adj[i + EPT], s2 = adj[i + 2 * EPT], s3 = adj[i + 3 * EPT];
            uint4 u0 = g4[(size_t)s0 * Q8 + q];
            uint4 u1 = g4[(size_t)s1 * Q8 + q];
            uint4 u2 = g4[(size_t)s2 * Q8 + q];
            uint4 u3 = g4[(size_t)s3 * Q8 + q];
            ACCU(u0); ACCU(u1); ACCU(u2); ACCU(u3);
        }
        for (; i < end; i += EPT) {
            int sv = adj[i];
            uint4 u = g4[(size_t)sv * Q8 + q];
            ACCU(u);
        }
#pragma unroll
        for (int d = Q8; d < 64; d <<= 1)
#pragma unroll
            for (int c = 0; c < 8; ++c) acc[c] += __shfl_xor(acc[c], d, 64);
        if (eg == 0) {
            float4* sp = (float4*)&sagg[wid][q * 8];
            sp[0] = make_float4(acc[0], acc[1], acc[2], acc[3]);
            sp[1] = make_float4(acc[4], acc[5], acc[6], acc[7]);
        }
    }
    __syncthreads();
    if (active && lane < DOUT) {
        float rv = bfs(r[(size_t)v * DOUT + lane]);
        sh[wid][lane] = fmaxf(fmaf(sagg[wid][lane], invc[v], rv), 0.f);
    }
    __syncthreads();
    constexpr int TOT = WAVES * DNEXT * 2;
    if (threadIdx.x < TOT) {
        int j = threadIdx.x % DNEXT;
        int node = (threadIdx.x / DNEXT) % WAVES;
        int m = threadIdx.x / (DNEXT * WAVES);
        int vv = blockIdx.x * WAVES + node;
        if (vv < N) {
            const float* W = m ? sWr : sWl;
            float a = m ? sbn[j] : 0.f;
#pragma unroll
            for (int k = 0; k < DOUT; ++k) a = fmaf(sh[node][k], W[k * DNEXT + j], a);
            unsigned short bv = (unsigned short)f2bf(a);
            if (m) rnext[(size_t)vv * DNEXT + j] = bv;
            else   gnext[(size_t)vv * DNEXT + j] = bv;
        }
    }
}

// ---- final agg (DOUT=16) + fused 16->1 head ----
template <int WAVES>
__global__ void aggh_k(const unsigned* __restrict__ g, const int* __restrict__ off,
                       const int* __restrict__ adj, const float* __restrict__ invc,
                       const unsigned short* __restrict__ r, const float* __restrict__ Wc,
                       const float* __restrict__ bc, float* __restrict__ out, int N) {
    constexpr int DOUT = 16, Q8 = 2, EPT = 32;
    __shared__ float sagg[WAVES][DOUT];
    int wid = threadIdx.x >> 6, lane = threadIdx.x & 63;
    int v = blockIdx.x * WAVES + wid;
    bool active = v < N;
    int q = lane & (Q8 - 1);
    int eg = lane / Q8;
    float acc[8] = {0, 0, 0, 0, 0, 0, 0, 0};
    if (active) {
        int beg = off[v], end = off[v + 1];
        const uint4* g4 = (const uint4*)g;
        int i = beg + eg;
        for (; i + 3 * EPT < end; i += 4 * EPT) {
            int s0 = adj[i], s1 = adj[i + EPT], s2 = adj[i + 2 * EPT], s3 = adj[i + 3 * EPT];
            uint4 u0 = g4[(size_t)s0 * Q8 + q];
            uint4 u1 = g4[(size_t)s1 * Q8 + q];
            uint4 u2 = g4[(size_t)s2 * Q8 + q];
            uint4 u3 = g4[(size_t)s3 * Q8 + q];
            ACCU(u0); ACCU(u1); ACCU(u2); ACCU(u3);
        }
        for (; i < end; i += EPT) {
            int sv = adj[i];
            uint4 u = g4[(size_t)sv * Q8 + q];
            ACCU(u);
        }
#pragma unroll
        for (int d = Q8; d < 64; d <<= 1)
#pragma unroll
            for (int c = 0; c < 8; ++c) acc[c] += __shfl_xor(acc[c], d, 64);
        if (eg == 0) {
            float4* sp = (float4*)&sagg[wid][q * 8];
            sp[0] = make_float4(acc[0], acc[1], acc[2], acc[3]);
            sp[1] = make_float4(acc[4], acc[5], acc[6], acc[7]);
        }
    }
#undef ACCU
    __syncthreads();
    if (active && lane < DOUT) {
        float rv = bfs(r[(size_t)v * DOUT + lane]);
        float val = fmaxf(fmaf(sagg[wid][lane], invc[v], rv), 0.f);
        float pp = val * Wc[lane];
#pragma unroll
        for (int d = 1; d < 16; d <<= 1) pp += __shfl_xor(pp, d, 64);
        if (lane == 0) out[v] = pp + bc[0];
    }
}

extern "C" void kernel_launch(void* const* d_in, const int* in_sizes, int n_in,
                              void* d_out, int out_size, void* d_ws, size_t ws_size,
                              hipStream_t stream) {
    const float* x   = (const float*)d_in[0];
    const int*   ei  = (const int*)d_in[1];
    const float* Wl0 = (const float*)d_in[2];
    const float* Wr0 = (const float*)d_in[3];
    const float* b0  = (const float*)d_in[4];
    const float* Wl1 = (const float*)d_in[5];
    const float* Wr1 = (const float*)d_in[6];
    const float* b1  = (const float*)d_in[7];
    const float* Wl2 = (const float*)d_in[8];
    const float* Wr2 = (const float*)d_in[9];
    const float* b2  = (const float*)d_in[10];
    const float* Wc  = (const float*)d_in[11];
    const float* bc  = (const float*)d_in[12];
    float* out = (float*)d_out;

    const int N = NN;
    const int E = in_sizes[1] / 2;
    const int* src = ei;
    const int* dst = ei + E;

    char* ws = (char*)d_ws;
    const size_t MB = 1 << 20;
    int*      gcnt = (int*)(ws + 0);               // [HB][NBK] counts, 400 KB
    int*      goff = (int*)(ws + 1 * MB);          // [HB][NBK] local offs, 400 KB
    int*      bb   = (int*)(ws + 2 * MB);          // (NBK+1) bucket bases
    int*      off  = (int*)(ws + 3 * MB);          // 400 KB + 4
    float*    inv  = (float*)(ws + 3 * MB + 512 * 1024);
    unsigned* pair = (unsigned*)(ws + 4 * MB);     // 12.8e6 B, block-major (dead after sort2)
    int*      adj  = (int*)(ws + 17 * MB);         // 12.8e6 B CSR adjacency (live all layers)
    unsigned*       g0 = (unsigned*)(ws + 30 * MB);          // N*32 u32 = 12.8e6
    unsigned*       r0 = (unsigned*)(ws + 43 * MB);          // N*32 u32 (bf16x2) = 12.8e6
    unsigned short* g1 = (unsigned short*)(ws + 4 * MB);     // N*32 bf16 = 6.4e6 (pair dead); 16B-aligned
    unsigned short* r1 = (unsigned short*)(ws + 4 * MB + 6400000);  // N*32 bf16 = 6.4e6
    unsigned short* g2 = (unsigned short*)(ws + 30 * MB);    // N*16 bf16 = 3.2e6 (g0 dead); 16B-aligned
    unsigned short* r2 = (unsigned short*)(ws + 34 * MB);    // N*16 bf16 = 3.2e6

    // ---- counting-sort CSR build: 3 kernels, no global atomics,
    //      all global writes full-line via LDS staging ----
    part1_k<<<HB, 512, 0, stream>>>(src, dst, E, gcnt, goff, pair);
    bsum_k<<<1, 512, 0, stream>>>(gcnt, bb, E);
    sort2_k<<<NBK, HB, 0, stream>>>(pair, goff, bb, adj, off, inv, N, E);

    // ---- layer 0 transform: x -> g0 (bf16), r0 (bf16) ----
    transform2_k<64, 64><<<(N / 2 * 32 + 255) / 256, 256, 0, stream>>>(x, Wl0, Wr0, b0, g0, r0, N);
    // ---- agg L0 + transform L1 fused: -> g1, r1 (h1 never in global) ----
    aggt_k<64, 32, 4><<<(N + 3) / 4, 256, 0, stream>>>(g0, off, adj, inv,
        (const unsigned short*)r0, Wl1, Wr1, b1, g1, r1, N);
    // ---- agg L1 + transform L2 fused: -> g2, r2 ----
    aggt_k<32, 16, 4><<<(N + 3) / 4, 256, 0, stream>>>((const unsigned*)g1, off, adj, inv,
        r1, Wl2, Wr2, b2, g2, r2, N);
    // ---- agg L2 + head fused: -> out ----
    aggh_k<4><<<(N + 3) / 4, 256, 0, stream>>>((const unsigned*)g2, off, adj, inv, r2, Wc, bc, out, N);
}